// Round 5
// baseline (2316.674 us; speedup 1.0000x reference)
//
#include <hip/hip_runtime.h>
#include <math.h>

// Problem constants
#define B_SZ    4096
#define D_DIM   128
#define K_CODES 8192
#define RECON_N (4096*84*84)   // 28901376

// ============================ VQ argmin + losses ============================
// Exact numpy-f32 semantics (verified R2/R3): d2q = fl32(zz - 2r), r = sequential
// f32 FMA chain over d ascending, zz = numpy pairwise-8. Ties -> lowest index.
__global__ __attribute__((amdgpu_flat_work_group_size(1024,1024),
                          amdgpu_waves_per_eu(4,8)))
void vq_kernel(
    const float* __restrict__ z, const float* __restrict__ cb,
    int* __restrict__ idx_ws, float* __restrict__ out_idx_f,
    double* __restrict__ lpart)
{
  __shared__ float z_s[16][128];
  __shared__ float zz_s[16];
  __shared__ float redv[16][16];   // [wave][row]
  __shared__ int   redi[16][16];
  __shared__ int   win[16];
  __shared__ double wsum[16];
  const int t  = threadIdx.x;
  const int b0 = blockIdx.x * 16;

  for (int p = t; p < 2048; p += 1024) z_s[p >> 7][p & 127] = z[(size_t)b0*128 + p];
  __syncthreads();

  // numpy pairwise-8 emulation of (z*z).sum(axis=1); separate mul/add roundings
  if (t < 16) {
    #pragma clang fp contract(off)
    const float* a = z_s[t];
    float r8[8];
    #pragma unroll
    for (int j = 0; j < 8; j++) { float v = a[j]*a[j]; r8[j] = v; }
    for (int i = 8; i < 128; i += 8) {
      #pragma unroll
      for (int j = 0; j < 8; j++) { float v = a[i+j]*a[i+j]; r8[j] = r8[j] + v; }
    }
    zz_s[t] = ((r8[0]+r8[1]) + (r8[2]+r8[3])) + ((r8[4]+r8[5]) + (r8[6]+r8[7]));
  }
  __syncthreads();

  const int lane = t & 63, wv = t >> 6;
  float zzr[16];
  #pragma unroll
  for (int row = 0; row < 16; row++) zzr[row] = zz_s[row];

  float best[16]; int bid[16];
  #pragma unroll
  for (int row = 0; row < 16; row++) { best[row] = INFINITY; bid[row] = 0; }

  #pragma unroll 1
  for (int k = 0; k < 8; k++) {
    const int cg   = wv + (k << 4);        // 16 waves cover 128 groups of 64 codes
    const int code = (cg << 6) + lane;     // ascending in k for fixed lane
    const float* ep = cb + (size_t)code * 128;
    float r[16];
    #pragma unroll
    for (int row = 0; row < 16; row++) r[row] = 0.0f;
    #pragma unroll 1
    for (int d16 = 0; d16 < 8; d16++) {
      const float4 e0 = *(const float4*)(ep + d16*16 + 0);
      const float4 e1 = *(const float4*)(ep + d16*16 + 4);
      const float4 e2 = *(const float4*)(ep + d16*16 + 8);
      const float4 e3 = *(const float4*)(ep + d16*16 + 12);
      #pragma unroll
      for (int row = 0; row < 16; row++) {
        const float4 z0 = *(const float4*)(&z_s[row][d16*16 + 0]);   // uniform -> broadcast
        const float4 z1 = *(const float4*)(&z_s[row][d16*16 + 4]);
        const float4 z2 = *(const float4*)(&z_s[row][d16*16 + 8]);
        const float4 z3 = *(const float4*)(&z_s[row][d16*16 + 12]);
        float rr = r[row];
        // single dependent FMA chain, d ascending — identical to R3 (bit-exact)
        rr = fmaf(z0.x,e0.x,rr); rr = fmaf(z0.y,e0.y,rr); rr = fmaf(z0.z,e0.z,rr); rr = fmaf(z0.w,e0.w,rr);
        rr = fmaf(z1.x,e1.x,rr); rr = fmaf(z1.y,e1.y,rr); rr = fmaf(z1.z,e1.z,rr); rr = fmaf(z1.w,e1.w,rr);
        rr = fmaf(z2.x,e2.x,rr); rr = fmaf(z2.y,e2.y,rr); rr = fmaf(z2.z,e2.z,rr); rr = fmaf(z2.w,e2.w,rr);
        rr = fmaf(z3.x,e3.x,rr); rr = fmaf(z3.y,e3.y,rr); rr = fmaf(z3.z,e3.z,rr); rr = fmaf(z3.w,e3.w,rr);
        r[row] = rr;
      }
    }
    #pragma unroll
    for (int row = 0; row < 16; row++) {
      const float tt = fmaf(-2.0f, r[row], zzr[row]);  // fl32(zz - 2r), single rounding
      if (tt < best[row]) { best[row] = tt; bid[row] = code; }
    }
  }

  // cross-lane lex argmin per row (tie -> smaller index)
  #pragma unroll 1
  for (int row = 0; row < 16; row++) {
    float v = best[row]; int i = bid[row];
    #pragma unroll
    for (int m = 32; m; m >>= 1) {
      float v2 = __shfl_xor(v, m, 64);
      int   i2 = __shfl_xor(i, m, 64);
      if (v2 < v || (v2 == v && i2 < i)) { v = v2; i = i2; }
    }
    if (lane == 0) { redv[wv][row] = v; redi[wv][row] = i; }
  }
  __syncthreads();

  if (t < 16) {   // row t: reduce over 16 waves
    float v = redv[0][t]; int i = redi[0][t];
    #pragma unroll 1
    for (int w = 1; w < 16; w++) {
      float v2 = redv[w][t]; int i2 = redi[w][t];
      if (v2 < v || (v2 == v && i2 < i)) { v = v2; i = i2; }
    }
    win[t] = i;
    idx_ws[b0 + t] = i;
    out_idx_f[b0 + t] = (float)i;   // float out; exact for idx < 2^24
  }
  __syncthreads();

  // loss partial: sum (z - e_win)^2 over 16 rows (f64; threshold slack huge)
  double ls = 0.0;
  for (int p = t; p < 2048; p += 1024) {
    int r = p >> 7, d = p & 127;
    float diff = z_s[r][d] - cb[(size_t)win[r]*128 + d];
    ls = fma((double)diff, (double)diff, ls);
  }
  #pragma unroll
  for (int m = 32; m; m >>= 1) ls += __shfl_xor(ls, m, 64);
  if (lane == 0) wsum[wv] = ls;
  __syncthreads();
  if (t == 0) {
    double s = 0.0;
    for (int w = 0; w < 16; w++) s += wsum[w];
    lpart[blockIdx.x] = s;
  }
}

__global__ __launch_bounds__(256) void fin_kernel(const double* __restrict__ lpart,
                                                  float* __restrict__ out_loss)
{
  __shared__ double s[256];
  const int t = threadIdx.x;
  s[t] = lpart[t];
  __syncthreads();
  for (int off = 128; off; off >>= 1) {
    if (t < off) s[t] += s[t + off];
    __syncthreads();
  }
  if (t == 0) {
    float l = (float)(s[0] / (4096.0*128.0));
    out_loss[0] = l;   // codebook_loss
    out_loss[1] = l;   // commitment_loss (same value)
  }
}

// ===================== linear: x1[b,o] = cb[idx[b]] . lin_w[o] + lin_b[o] ====
__global__ __launch_bounds__(256) void linear_kernel(
    const float* __restrict__ cb, const int* __restrict__ idx,
    const float* __restrict__ lw, const float* __restrict__ lb,
    float* __restrict__ x1)
{
  __shared__ float As[64][65];
  __shared__ float Bs[64][65];
  __shared__ int idx_s[64];
  const int t  = threadIdx.x;
  const int b0 = blockIdx.x * 64, n0 = blockIdx.y * 64;
  if (t < 64) idx_s[t] = idx[b0 + t];
  float acc[4][4] = {{0.f}};
  const int tr = (t >> 4)*4, tc = (t & 15)*4;
  for (int d0 = 0; d0 < 128; d0 += 64) {
    __syncthreads();
    #pragma unroll
    for (int l = 0; l < 16; l++) {
      int flat = t + l*256;
      int r = flat >> 6, d = flat & 63;
      As[r][d] = cb[(size_t)idx_s[r]*128 + d0 + d];
      Bs[r][d] = lw[(size_t)(n0 + r)*128 + d0 + d];
    }
    __syncthreads();
    #pragma unroll 8
    for (int d = 0; d < 64; d++) {
      float a0 = As[tr+0][d], a1 = As[tr+1][d], a2 = As[tr+2][d], a3 = As[tr+3][d];
      float q0 = Bs[tc+0][d], q1 = Bs[tc+1][d], q2 = Bs[tc+2][d], q3 = Bs[tc+3][d];
      acc[0][0] = fmaf(a0,q0,acc[0][0]); acc[0][1] = fmaf(a0,q1,acc[0][1]);
      acc[0][2] = fmaf(a0,q2,acc[0][2]); acc[0][3] = fmaf(a0,q3,acc[0][3]);
      acc[1][0] = fmaf(a1,q0,acc[1][0]); acc[1][1] = fmaf(a1,q1,acc[1][1]);
      acc[1][2] = fmaf(a1,q2,acc[1][2]); acc[1][3] = fmaf(a1,q3,acc[1][3]);
      acc[2][0] = fmaf(a2,q0,acc[2][0]); acc[2][1] = fmaf(a2,q1,acc[2][1]);
      acc[2][2] = fmaf(a2,q2,acc[2][2]); acc[2][3] = fmaf(a2,q3,acc[2][3]);
      acc[3][0] = fmaf(a3,q0,acc[3][0]); acc[3][1] = fmaf(a3,q1,acc[3][1]);
      acc[3][2] = fmaf(a3,q2,acc[3][2]); acc[3][3] = fmaf(a3,q3,acc[3][3]);
    }
  }
  #pragma unroll
  for (int i = 0; i < 4; i++)
    #pragma unroll
    for (int j = 0; j < 4; j++)
      x1[(size_t)(b0 + tr + i)*3136 + n0 + tc + j] = acc[i][j] + lb[n0 + tc + j];
}

// ===================== decoder_a: conv1 + conv2, compact-LDS 1 img/block =====
// R5 (this session): residency theory v2 — schedulable LDS/CU may be 128 KiB
// (not 160): R0 (2x66560B) and R1 (2x65536B, exactly at the boundary) both got
// 1 block/CU. Test with LDS WELL below 64 KiB/block via compact halo storage:
// halo rows 0/15 are all-zero for every channel -> store only rows 1..14
// (224 floats + 4 pad = 228/ch) plus ONE shared 16-float zero row. Row pointers
// redirect r==0/15 to the zero row branchlessly (per-thread base + per-i stride
// that is 0 for the zero row). LDS = (16 + 64*228)*4 = 58432 B -> two
// 896-thread blocks = 116.9 KiB + 1792 threads: co-residency possible under
// every known limit. Keeps R3/R4's full-28-row conv2 + aligned stores; loses
// the 2-image weight amortization (L1-hot, minor). Bit-identical FMA chains.
#define DA_T 896
#define B1_CS 228            // compact channel stride (floats): 14 rows x 16 + 4 pad; %32==4
#define DA_LDS_FL (16 + 64*B1_CS)   // 14608 floats = 58432 B
__global__ __attribute__((amdgpu_flat_work_group_size(DA_T, DA_T),
                          amdgpu_waves_per_eu(4, 8)))
void decoder_a(
    const float* __restrict__ x1,
    const float* __restrict__ w1, const float* __restrict__ b1,
    const float* __restrict__ w2, const float* __restrict__ b2,
    float* __restrict__ a2, int b_off)
{
  extern __shared__ float B1s[];   // [0..15] zero row; ch i rows 1..14 at 16+i*228
  const int tid = threadIdx.x;
  const int b   = blockIdx.x;        // local image index (chunk buffer)
  const int bg  = b + b_off;         // global image index

  if (tid < 16) B1s[tid] = 0.0f;     // shared zero halo row
  __syncthreads();

  // ---- conv1: (64,7,7) -> (64,14,14), relu. item = (c=tid&63, y=tid>>6) ----
  {
    const int c = tid & 63, y = tid >> 6;
    const int ky0 = (y & 1) ? 0 : 1;
    const int iy0 = (y + 1 - ky0) >> 1;   // valid if <7
    const int iy1 = iy0 - 1;              // valid if >=0
    const bool v0 = (iy0 < 7), v1 = (iy1 >= 0);   // wave-uniform (y = wave idx)
    float acc[14];
    const float bias = b1[c];
    #pragma unroll
    for (int x = 0; x < 14; x++) acc[x] = bias;
    const float* xim = x1 + (size_t)bg*3136;
    #pragma unroll 1
    for (int i = 0; i < 64; i++) {
      const float* wp = w1 + (((i << 6) + c) << 4) + ky0*4;
      const float4 wA4 = *(const float4*)(wp);
      const float4 wB4 = *(const float4*)(wp + 8);
      const float wa[4] = {wA4.x, wA4.y, wA4.z, wA4.w};
      const float wb[4] = {wB4.x, wB4.y, wB4.z, wB4.w};
      float r0[7], r1[7];
      if (v0) {
        const float* xr = xim + i*49 + iy0*7;
        #pragma unroll
        for (int j = 0; j < 7; j++) r0[j] = xr[j];
      } else {
        #pragma unroll
        for (int j = 0; j < 7; j++) r0[j] = 0.0f;
      }
      if (v1) {
        const float* xr = xim + i*49 + iy1*7;
        #pragma unroll
        for (int j = 0; j < 7; j++) r1[j] = xr[j];
      } else {
        #pragma unroll
        for (int j = 0; j < 7; j++) r1[j] = 0.0f;
      }
      #pragma unroll
      for (int x = 0; x < 14; x++) {
        const int kxs = (x & 1) ? 0 : 1;
        const int ix0 = (x + 1 - kxs) >> 1;
        const int ix1 = ix0 - 1;
        float s = acc[x];
        if (ix0 < 7)  { s = fmaf(r0[ix0], wa[kxs],   s); s = fmaf(r1[ix0], wb[kxs],   s); }
        if (ix1 >= 0) { s = fmaf(r0[ix1], wa[kxs+2], s); s = fmaf(r1[ix1], wb[kxs+2], s); }
        acc[x] = s;
      }
    }
    // write compact halo row (y+1) -> slot y: cols 0..15 with zero ends, 4x b128
    float* o = &B1s[16 + c*B1_CS + y*16];
    #pragma unroll
    for (int x = 0; x < 14; x++) acc[x] = fmaxf(acc[x], 0.0f);
    *(float4*)(o + 0)  = make_float4(0.0f,    acc[0],  acc[1],  acc[2]);
    *(float4*)(o + 4)  = make_float4(acc[3],  acc[4],  acc[5],  acc[6]);
    *(float4*)(o + 8)  = make_float4(acc[7],  acc[8],  acc[9],  acc[10]);
    *(float4*)(o + 12) = make_float4(acc[11], acc[12], acc[13], 0.0f);
  }
  __syncthreads();

  // ---- conv2: (64,14,14) -> (32,28,28), relu. item = (c=tid&31, y=tid>>5) ----
  // Full 28-wide row per thread; rows via compact pointers w/ zero-row redirect.
  {
    const int c = tid & 31, y = tid >> 5;
    const int ky0 = (y & 1) ? 0 : 1;
    const int iy0 = (y + 1 - ky0) >> 1;     // 0..14
    const int row0 = iy0 + 1;               // halo row for ky0   (1..15)
    const int row1 = iy0;                   // halo row for ky0+2 (0..14)
    const bool z0 = (row0 == 15);           // all-zero halo row?
    const bool z1 = (row1 == 0);
    const float* p0 = z0 ? B1s : (B1s + 16 + (row0 - 1)*16);
    const float* p1 = z1 ? B1s : (B1s + 16 + (row1 - 1)*16);
    const int s0 = z0 ? 0 : B1_CS;          // per-i stride (0 pins the zero row)
    const int s1 = z1 ? 0 : B1_CS;
    const float bias = b2[c];
    float acc[28];
    #pragma unroll
    for (int x = 0; x < 28; x++) acc[x] = bias;
    #pragma unroll 1
    for (int i = 0; i < 64; i++) {
      const float* wp = w2 + (((i << 5) + c) << 4) + ky0*4;
      const float4 wA4 = *(const float4*)(wp);
      const float4 wB4 = *(const float4*)(wp + 8);
      const float wa[4] = {wA4.x, wA4.y, wA4.z, wA4.w};
      const float wb[4] = {wB4.x, wB4.y, wB4.z, wB4.w};
      float r0[16], r1[16];
      #pragma unroll
      for (int q = 0; q < 4; q++) {
        const float4 a4 = *(const float4*)(p0 + q*4);
        r0[q*4+0]=a4.x; r0[q*4+1]=a4.y; r0[q*4+2]=a4.z; r0[q*4+3]=a4.w;
      }
      #pragma unroll
      for (int q = 0; q < 4; q++) {
        const float4 a4 = *(const float4*)(p1 + q*4);
        r1[q*4+0]=a4.x; r1[q*4+1]=a4.y; r1[q*4+2]=a4.z; r1[q*4+3]=a4.w;
      }
      p0 += s0; p1 += s1;
      #pragma unroll
      for (int x = 0; x < 28; x++) {
        const int kxs = (x & 1) ? 0 : 1;
        const int col = ((x + 1 - kxs) >> 1) + 1;   // 1..15
        float s = acc[x];
        s = fmaf(r0[col],   wa[kxs],   s);
        s = fmaf(r1[col],   wb[kxs],   s);
        s = fmaf(r0[col-1], wa[kxs+2], s);
        s = fmaf(r1[col-1], wb[kxs+2], s);
        acc[x] = s;
      }
    }
    // ---- epilogue: relu + store row (28 floats contiguous) ----
    float* st = a2 + (size_t)b*25088 + c*784 + y*28;
    #pragma unroll
    for (int x = 0; x < 28; x++) acc[x] = fmaxf(acc[x], 0.0f);
    #pragma unroll
    for (int q = 0; q < 7; q++)
      *(float4*)(st + q*4) = make_float4(acc[q*4+0],acc[q*4+1],acc[q*4+2],acc[q*4+3]);
  }
}

// ============ decoder_b: conv3 + bilinear resize 56->84 + tanh ==============
#define DB_T 896
__global__ __attribute__((amdgpu_flat_work_group_size(DB_T, DB_T)))
void decoder_b(
    const float* __restrict__ a2,
    const float* __restrict__ w3, const float* __restrict__ b3,
    float* __restrict__ out, int b_off)
{
  extern __shared__ float lds[];
  float* Cs  = lds;           // 25088 (a2 image, [c][y][x])
  float* Ds  = lds + 25088;   // 3136  (conv3 out, 56x56)
  float* W3s = lds + 28224;   // 512
  const int tid = threadIdx.x;
  const int b   = blockIdx.x;
  const int bg  = b + b_off;

  {
    const float4* src = (const float4*)(a2 + (size_t)b*25088);
    for (int p = tid; p < 6272; p += DB_T) ((float4*)Cs)[p] = src[p];
    for (int p = tid; p < 512; p += DB_T) W3s[p] = w3[p];
  }
  __syncthreads();

  if (tid < 784) {   // item = (y=tid/14 in 0..55, xq=tid%14), 4 px each
    const int y = tid / 14, xq = tid - y*14;
    const int x0 = xq * 4;
    const int ky0 = (y & 1) ? 0 : 1;
    const int iy0 = (y + 1 - ky0) >> 1;   // valid if <28
    const int iy1 = iy0 - 1;              // valid if >=0
    const bool v0 = (iy0 < 28), v1 = (iy1 >= 0);
    const int ixb = (x0 >> 1) - 1;        // input col for j=0
    float acc[4];
    const float bias = b3[0];
    #pragma unroll
    for (int x = 0; x < 4; x++) acc[x] = bias;
    #pragma unroll 1
    for (int i = 0; i < 32; i++) {
      const float* wr = &W3s[i*16 + ky0*4];
      float wa[4], wb[4];
      #pragma unroll
      for (int k = 0; k < 4; k++) { wa[k] = wr[k]; wb[k] = wr[8 + k]; }
      const float* Ci = &Cs[i*784];
      float r0[4], r1[4];
      #pragma unroll
      for (int j = 0; j < 4; j++) {
        const int ix = ixb + j;
        const bool vx = (ix >= 0) && (ix < 28);
        r0[j] = (v0 && vx) ? Ci[iy0*28 + ix] : 0.0f;
        r1[j] = (v1 && vx) ? Ci[iy1*28 + ix] : 0.0f;
      }
      #pragma unroll
      for (int xl = 0; xl < 4; xl++) {
        const int kxs = (xl & 1) ? 0 : 1;     // x0 even
        const int j = ((x0 + xl + 1 - kxs) >> 1) - ixb;   // 1..3
        float s = acc[xl];
        s = fmaf(r0[j],   wa[kxs],   s);
        s = fmaf(r1[j],   wb[kxs],   s);
        s = fmaf(r0[j-1], wa[kxs+2], s);
        s = fmaf(r1[j-1], wb[kxs+2], s);
        acc[xl] = s;
      }
    }
    *(float4*)(&Ds[y*56 + x0]) = make_float4(acc[0],acc[1],acc[2],acc[3]);
  }
  __syncthreads();

  // bilinear resize 56->84 (half-pixel, edge clamp == jax renorm) + tanh
  for (int p = tid; p < 84*84; p += DB_T) {
    const int oy = p / 84, ox = p - oy*84;
    const float sy = (oy + 0.5f)*(2.0f/3.0f) - 0.5f;
    const float sx = (ox + 0.5f)*(2.0f/3.0f) - 0.5f;
    const int y0 = (int)floorf(sy), x0i = (int)floorf(sx);
    const float fy = sy - (float)y0, fx = sx - (float)x0i;
    const int y0c = y0 < 0 ? 0 : y0, y1c = (y0 + 1 > 55) ? 55 : (y0 + 1);
    const int x0c = x0i < 0 ? 0 : x0i, x1c = (x0i + 1 > 55) ? 55 : (x0i + 1);
    const float v00 = Ds[y0c*56 + x0c], v01 = Ds[y0c*56 + x1c];
    const float v10 = Ds[y1c*56 + x0c], v11 = Ds[y1c*56 + x1c];
    const float v = (v00*(1.0f - fx) + v01*fx)*(1.0f - fy)
                  + (v10*(1.0f - fx) + v11*fx)*fy;
    out[(size_t)bg*7056 + p] = tanhf(v);
  }
}

// ================================ launch ====================================
extern "C" void kernel_launch(void* const* d_in, const int* in_sizes, int n_in,
                              void* d_out, int out_size, void* d_ws, size_t ws_size,
                              hipStream_t stream) {
  (void)in_sizes; (void)n_in; (void)out_size;
  const float* z  = (const float*)d_in[0];
  const float* cb = (const float*)d_in[1];
  const float* lw = (const float*)d_in[2];
  const float* lb = (const float*)d_in[3];
  const float* w1 = (const float*)d_in[4];
  const float* b1 = (const float*)d_in[5];
  const float* w2 = (const float*)d_in[6];
  const float* b2 = (const float*)d_in[7];
  const float* w3 = (const float*)d_in[8];
  const float* b3 = (const float*)d_in[9];

  float* out      = (float*)d_out;
  float* out_idx  = out + RECON_N;          // 4096 indices as float
  float* out_loss = out + RECON_N + 4096;   // 2 losses

  char*   ws     = (char*)d_ws;
  double* lpart  = (double*)ws;             // 256 doubles
  int*    idx_ws = (int*)(ws + 4096);       // 4096 ints
  float*  x1     = (float*)(ws + 32768);    // 4096*3136 floats (51.4 MB)
  const size_t a2_off = 32768 + (size_t)4096*3136*4;
  float*  a2     = (float*)(ws + a2_off);   // up to 4096*25088 floats (411 MB)

  // chunk the decoder if ws is too small for the full a2 buffer
  long long avail = (long long)ws_size - (long long)a2_off;
  int cap = (int)(avail / (25088*4));
  if (cap > 4096) cap = 4096;
  if (cap < 1) cap = 1;

  vq_kernel<<<256, 1024, 0, stream>>>(z, cb, idx_ws, out_idx, lpart);
  fin_kernel<<<1, 256, 0, stream>>>(lpart, out_loss);
  linear_kernel<<<dim3(64, 49), 256, 0, stream>>>(cb, idx_ws, lw, lb, x1);

  const int da_lds = DA_LDS_FL*4;          // 58432 B -> 2 blocks/CU target
  const int db_lds = (25088+3136+512)*4;   // 114944 B
  hipFuncSetAttribute((const void*)decoder_a,
                      hipFuncAttributeMaxDynamicSharedMemorySize, da_lds);
  hipFuncSetAttribute((const void*)decoder_b,
                      hipFuncAttributeMaxDynamicSharedMemorySize, db_lds);
  for (int b0 = 0; b0 < B_SZ; b0 += cap) {
    const int n = (B_SZ - b0 < cap) ? (B_SZ - b0) : cap;
    decoder_a<<<n, DA_T, da_lds, stream>>>(x1, w1, b1, w2, b2, a2, b0);
    decoder_b<<<n, DB_T, db_lds, stream>>>(a2, w3, b3, out, b0);
  }
}